// Round 5
// baseline (453.904 us; speedup 1.0000x reference)
//
#include <hip/hip_runtime.h>
#include <hip/hip_bf16.h>
#include <math.h>

// Problem constants
constexpr int NB = 256;      // batch
constexpr int NL = 50;       // seq len
constexpr int ND = 128;      // dim
constexpr int NK = 4;        // interests
constexpr int NVm1 = 49999;  // V-1
constexpr int NPAD2 = 50176; // N padded to 392*128
constexpr int ROWS = NB * NL;   // 12800
constexpr int MROWS = NB * NK;  // 1024 (rows of select, b-major: row = b*4+k)
constexpr int GEMM_NSPAN = 512; // n cols per block in big GEMM (8 chunks of 64)
constexpr int MR = 64;          // rows per mega block

// prep kernel block ranges
constexpr int G_BN  = NPAD2 / 8;  // 6272 bnorm (8 rows/blk, float4 per thread)
constexpr int G_HW  = NB / 2;     // 128 hsW1 = (masked-mean hidden) @ att_w1 (2 b/blk)
constexpr int G_PP  = NL / 2;     // 25 posPart (2 rows/blk)
constexpr int G_XB  = ROWS * ND / 2048; // 800 Xb cast
constexpr int G_W1T = ND * ND / 256;    // 64
constexpr int G_AWT = ND * ND / 256;    // 64
constexpr int G_GLT = ND * 512 / 256;   // 256
constexpr int G_TOT = G_BN + G_HW + G_PP + G_XB + G_W1T + G_AWT + G_GLT;

typedef __bf16 bf16x8 __attribute__((ext_vector_type(8)));
typedef float f32x4 __attribute__((ext_vector_type(4)));

__device__ __forceinline__ float sigm_fast(float x) { return 1.0f / (1.0f + __expf(-x)); }
__device__ __forceinline__ float sigm_prec(float x) { return 1.0f / (1.0f + expf(-x)); }
__device__ __forceinline__ float fast_tanh(float x) {
    float xc = fminf(fmaxf(x, -15.f), 15.f);
    float e = __expf(2.f * xc);
    return (e - 1.f) / (e + 1.f);
}

__device__ __forceinline__ void gld_lds16(const void* g, void* l) {
    __builtin_amdgcn_global_load_lds(
        (const __attribute__((address_space(1))) void*)g,
        (__attribute__((address_space(3))) void*)l, 16, 0, 0);
}

// ---------------- K0: prep — bnorm, hsW1, posPart, Xb cast, weight transposes ----------------
__global__ __launch_bounds__(256) void k_prep(
    const float* __restrict__ hidden, const int* __restrict__ mask,
    const float* __restrict__ pos_emb, const float* __restrict__ w1,
    const float* __restrict__ att_w1, const float* __restrict__ att_w2,
    const float* __restrict__ glu1_w, const float* __restrict__ emb,
    float* __restrict__ hsW1, float* __restrict__ posPart,
    __hip_bfloat16* __restrict__ XbG, __hip_bfloat16* __restrict__ w1h_t,
    __hip_bfloat16* __restrict__ attw2_t, __hip_bfloat16* __restrict__ glu_t,
    __hip_bfloat16* __restrict__ bnv, float* __restrict__ loss_out) {
    __shared__ float sPP[2 * ND];
    int blk = blockIdx.x, tid = threadIdx.x;
    if (blk < G_BN) {
        int v = blk * 8 + (tid >> 5);
        int j = (tid & 31) << 2;
        float4 x = make_float4(0.f, 0.f, 0.f, 0.f);
        if (v < NVm1) x = *(const float4*)&emb[((size_t)v + 1) * ND + j];
        float ss = x.x * x.x + x.y * x.y + x.z * x.z + x.w * x.w;
#pragma unroll
        for (int off = 16; off >= 1; off >>= 1) ss += __shfl_xor(ss, off);
        float rn = 1.f / fmaxf(sqrtf(ss), 1e-12f);
        union { ushort4 u4; __hip_bfloat16 h[4]; } o;
        o.h[0] = __float2bfloat16(x.x * rn);
        o.h[1] = __float2bfloat16(x.y * rn);
        o.h[2] = __float2bfloat16(x.z * rn);
        o.h[3] = __float2bfloat16(x.w * rn);
        *(ushort4*)&bnv[(size_t)v * ND + j] = o.u4;
    } else if (blk < G_BN + G_HW) {
        int half = tid >> 7, d = tid & 127;
        int b = (blk - G_BN) * 2 + half;
        float acc = 0.f, msum = 0.f;
        for (int l = 0; l < NL; ++l) {
            float mv = (float)mask[b * NL + l];
            acc += hidden[((size_t)b * NL + l) * ND + d] * mv;
            msum += mv;
        }
        sPP[half * ND + d] = acc / msum;
        __syncthreads();
        float o = 0.f;
#pragma unroll 8
        for (int j = 0; j < ND; ++j) o += sPP[half * ND + j] * att_w1[j * ND + d];
        hsW1[b * ND + d] = o;
        if (blk == G_BN && tid == 0) loss_out[0] = 0.f;
    } else if (blk < G_BN + G_HW + G_PP) {
        int rel = blk - (G_BN + G_HW);
        int rl = tid >> 7, d = tid & 127;
        int r = rel * 2 + rl;
        sPP[rl * ND + d] = pos_emb[r * ND + d];
        __syncthreads();
        float acc = 0.f;
#pragma unroll 8
        for (int j = 0; j < ND; ++j) acc += sPP[rl * ND + j] * w1[j * ND + d];
        posPart[r * ND + d] = acc;
    } else if (blk < G_BN + G_HW + G_PP + G_XB) {
        int rel = blk - (G_BN + G_HW + G_PP);
        size_t base = (size_t)rel * 2048 + (size_t)tid * 8;
        float4 f0 = *(const float4*)&hidden[base];
        float4 f1 = *(const float4*)&hidden[base + 4];
        union { bf16x8 v; __hip_bfloat16 h[8]; } u;
        u.h[0] = __float2bfloat16(f0.x); u.h[1] = __float2bfloat16(f0.y);
        u.h[2] = __float2bfloat16(f0.z); u.h[3] = __float2bfloat16(f0.w);
        u.h[4] = __float2bfloat16(f1.x); u.h[5] = __float2bfloat16(f1.y);
        u.h[6] = __float2bfloat16(f1.z); u.h[7] = __float2bfloat16(f1.w);
        *(bf16x8*)&XbG[base] = u.v;
    } else if (blk < G_BN + G_HW + G_PP + G_XB + G_W1T) {
        int i = (blk - (G_BN + G_HW + G_PP + G_XB)) * 256 + tid;
        int d = i >> 7, j = i & 127;
        w1h_t[d * ND + j] = __float2bfloat16(w1[(ND + j) * ND + d]);
    } else if (blk < G_BN + G_HW + G_PP + G_XB + G_W1T + G_AWT) {
        int i = (blk - (G_BN + G_HW + G_PP + G_XB + G_W1T)) * 256 + tid;
        int d = i >> 7, j = i & 127;
        attw2_t[d * ND + j] = __float2bfloat16(att_w2[j * ND + d]);
    } else {
        int i = (blk - (G_BN + G_HW + G_PP + G_XB + G_W1T + G_AWT)) * 256 + tid;
        int c = i >> 7, j = i & 127;
        glu_t[c * ND + j] = __float2bfloat16(glu1_w[j * 512 + c]);
    }
}

// ---------------- K1: mega — GEMM1(att,nh via MFMA) + alpha + GEMM2(glu) + beta ----------------
__global__ __launch_bounds__(256) void k_mega(
    const __hip_bfloat16* __restrict__ XbG, const __hip_bfloat16* __restrict__ w1h_t,
    const __hip_bfloat16* __restrict__ attw2_t, const __hip_bfloat16* __restrict__ glu_t,
    const float* __restrict__ hsW1, const float* __restrict__ att_v,
    const float* __restrict__ posPart, const float* __restrict__ glu1_b,
    const float* __restrict__ w2, const int* __restrict__ mask,
    float* __restrict__ beta_out) {
    __shared__ __hip_bfloat16 XbS[MR * ND];   // 16 KB swizzled
    __shared__ __hip_bfloat16 WS[ND * ND];    // 32 KB swizzled
    __shared__ __attribute__((aligned(16))) __hip_bfloat16 NHS[MR * 136]; // padded (+8)
    __shared__ float alphaS[MR * NK];
    __shared__ float hsW1S[3 * ND];
    int row0 = blockIdx.x * MR;
    int tid = threadIdx.x;
    int wave = tid >> 6, lane = tid & 63, l16 = lane & 15, quad = lane >> 4;
    int b0 = row0 / NL;

#pragma unroll
    for (int it = 0; it < 4; ++it) {
        int id = it * 256 + tid;
        int row = id >> 4, c = id & 15, gc = c ^ (row & 7);
        gld_lds16((const char*)XbG + ((size_t)(row0 + row) * 16 + gc) * 16,
                  (char*)XbS + (size_t)(it * 256 + wave * 64) * 16);
    }
#pragma unroll
    for (int it = 0; it < 8; ++it) {
        int id = it * 256 + tid;
        int row = id >> 4, c = id & 15, gc = c ^ (row & 7);
        gld_lds16((const char*)attw2_t + ((size_t)row * 16 + gc) * 16,
                  (char*)WS + (size_t)(it * 256 + wave * 64) * 16);
    }
    for (int i = tid; i < 3 * ND; i += 256) {
        int b = b0 + (i >> 7);
        hsW1S[i] = (b < NB) ? hsW1[b * ND + (i & 127)] : 0.f;
    }
    __syncthreads();

    const bf16x8* Xv = (const bf16x8*)XbS;
    const bf16x8* Wv = (const bf16x8*)WS;
    const bf16x8* Nv = (const bf16x8*)NHS; // row stride 17 (136 bf16)
    int arow = wave * 16 + l16;

    f32x4 acc8[8];
    // ---- GEMM1-att ----
#pragma unroll
    for (int ni = 0; ni < 8; ++ni) acc8[ni] = (f32x4){0.f, 0.f, 0.f, 0.f};
#pragma unroll
    for (int kk = 0; kk < 4; ++kk) {
        int ko = kk * 4 + quad;
        bf16x8 af = Xv[arow * 16 + (ko ^ (arow & 7))];
#pragma unroll
        for (int ni = 0; ni < 8; ++ni) {
            int n = ni * 16 + l16;
            bf16x8 bf = Wv[n * 16 + (ko ^ (n & 7))];
            acc8[ni] = __builtin_amdgcn_mfma_f32_16x16x32_bf16(af, bf, acc8[ni], 0, 0, 0);
        }
    }
#pragma unroll
    for (int r = 0; r < 4; ++r) {
        int lrow = wave * 16 + quad * 4 + r;
        int grow = row0 + lrow;
        int bb = grow / NL - b0;
        float a0 = 0.f, a1 = 0.f, a2 = 0.f, a3 = 0.f;
#pragma unroll
        for (int ni = 0; ni < 8; ++ni) {
            int col = ni * 16 + l16;
            float atv = fast_tanh(hsW1S[bb * ND + col] + acc8[ni][r]);
            float4 av = *(const float4*)&att_v[col * 4];
            a0 += atv * av.x; a1 += atv * av.y; a2 += atv * av.z; a3 += atv * av.w;
        }
#pragma unroll
        for (int off = 1; off < 16; off <<= 1) {
            a0 += __shfl_xor(a0, off); a1 += __shfl_xor(a1, off);
            a2 += __shfl_xor(a2, off); a3 += __shfl_xor(a3, off);
        }
        if (l16 == 0) {
            alphaS[lrow * 4 + 0] = sigm_fast(a0);
            alphaS[lrow * 4 + 1] = sigm_fast(a1);
            alphaS[lrow * 4 + 2] = sigm_fast(a2);
            alphaS[lrow * 4 + 3] = sigm_fast(a3);
        }
    }
    __syncthreads(); // WS reads done
#pragma unroll
    for (int it = 0; it < 8; ++it) {
        int id = it * 256 + tid;
        int row = id >> 4, c = id & 15, gc = c ^ (row & 7);
        gld_lds16((const char*)w1h_t + ((size_t)row * 16 + gc) * 16,
                  (char*)WS + (size_t)(it * 256 + wave * 64) * 16);
    }
    __syncthreads();
    // ---- GEMM1-nh ----
#pragma unroll
    for (int ni = 0; ni < 8; ++ni) acc8[ni] = (f32x4){0.f, 0.f, 0.f, 0.f};
#pragma unroll
    for (int kk = 0; kk < 4; ++kk) {
        int ko = kk * 4 + quad;
        bf16x8 af = Xv[arow * 16 + (ko ^ (arow & 7))];
#pragma unroll
        for (int ni = 0; ni < 8; ++ni) {
            int n = ni * 16 + l16;
            bf16x8 bf = Wv[n * 16 + (ko ^ (n & 7))];
            acc8[ni] = __builtin_amdgcn_mfma_f32_16x16x32_bf16(af, bf, acc8[ni], 0, 0, 0);
        }
    }
#pragma unroll
    for (int r = 0; r < 4; ++r) {
        int lrow = wave * 16 + quad * 4 + r;
        int grow = row0 + lrow;
        int l = grow % NL;
#pragma unroll
        for (int ni = 0; ni < 8; ++ni) {
            int col = ni * 16 + l16;
            float nhv = fast_tanh(posPart[l * ND + col] + acc8[ni][r]);
            NHS[lrow * 136 + col] = __float2bfloat16(nhv);
        }
    }
    __syncthreads(); // NHS complete, WS free
    // ---- GEMM2: 4 chunks of 128 cols; chunk ch == k-segment ch ----
    for (int ch = 0; ch < 4; ++ch) {
#pragma unroll
        for (int it = 0; it < 8; ++it) {
            int id = it * 256 + tid;
            int row = id >> 4, c = id & 15, gc = c ^ (row & 7);
            gld_lds16((const char*)glu_t + ((size_t)(ch * ND + row) * 16 + gc) * 16,
                      (char*)WS + (size_t)(it * 256 + wave * 64) * 16);
        }
        __syncthreads();
#pragma unroll
        for (int ni = 0; ni < 8; ++ni) acc8[ni] = (f32x4){0.f, 0.f, 0.f, 0.f};
#pragma unroll
        for (int kk = 0; kk < 4; ++kk) {
            int ko = kk * 4 + quad;
            bf16x8 af = Nv[arow * 17 + ko]; // padded, no swizzle
#pragma unroll
            for (int ni = 0; ni < 8; ++ni) {
                int n = ni * 16 + l16;
                bf16x8 bf = Wv[n * 16 + (ko ^ (n & 7))];
                acc8[ni] = __builtin_amdgcn_mfma_f32_16x16x32_bf16(af, bf, acc8[ni], 0, 0, 0);
            }
        }
#pragma unroll
        for (int r = 0; r < 4; ++r) {
            float s = 0.f;
#pragma unroll
            for (int ni = 0; ni < 8; ++ni) {
                int col = ni * 16 + l16;
                s += sigm_fast(acc8[ni][r] + glu1_b[ch * ND + col]) * w2[col * 4 + ch];
            }
#pragma unroll
            for (int off = 1; off < 16; off <<= 1) s += __shfl_xor(s, off);
            if (l16 == 0) {
                int lrow = wave * 16 + quad * 4 + r;
                int grow = row0 + lrow;
                float a = alphaS[lrow * 4 + ch];
                beta_out[(size_t)grow * 4 + ch] = s * (0.5f + a) * (float)mask[grow];
            }
        }
        __syncthreads();
    }
}

// ---------------- K2: loss (lens inline, atomic accumulate) ----------------
__global__ void k_loss(const float* __restrict__ beta, const int* __restrict__ mask,
                       float* __restrict__ loss_out) {
    int b = blockIdx.x;
    int t = threadIdx.x; // 64
    float mv = (t < NL) ? (float)mask[b * NL + t] : 0.f;
    float msum = mv;
    for (int off = 32; off >= 1; off >>= 1) msum += __shfl_xor(msum, off);
    float lens = msum - 5.0f; // LENGTH=5
    float bk[NK] = {0.f, 0.f, 0.f, 0.f};
    if (t < NL) {
#pragma unroll
        for (int k = 0; k < NK; ++k) bk[k] = beta[((size_t)b * NL + t) * NK + k];
    }
    float nb[NK];
#pragma unroll
    for (int k = 0; k < NK; ++k) {
        float v = bk[k] * bk[k];
        for (int off = 32; off >= 1; off >>= 1) v += __shfl_xor(v, off);
        nb[k] = bk[k] / fmaxf(sqrtf(v), 1e-12f);
    }
    float sim = 0.f;
#pragma unroll
    for (int i = 0; i < NK; ++i) {
#pragma unroll
        for (int j = 0; j < NK; ++j) {
            if (j > i) {
                float p = nb[i] * nb[j];
                for (int off = 32; off >= 1; off >>= 1) p += __shfl_xor(p, off);
                sim += fabsf(p);
            }
        }
    }
    sim *= (2.0f / (NK * (NK - 1)));
    if (t == 0) atomicAdd(loss_out, sigm_prec(sim * lens) * 0.01f); // BETA
}

// ---------------- K3: select -> bf16 (2 b per block) ----------------
__global__ __launch_bounds__(256) void k_select(
    const float* __restrict__ beta, const float* __restrict__ hidden,
    __hip_bfloat16* __restrict__ selb) {
    int b = blockIdx.x * 2 + (threadIdx.x >> 7);
    int d = threadIdx.x & 127;
    float a0 = 0.f, a1 = 0.f, a2 = 0.f, a3 = 0.f;
    for (int l = 0; l < NL; ++l) {
        float h = hidden[((size_t)b * NL + l) * ND + d];
        float4 bv = *(const float4*)&beta[((size_t)b * NL + l) * NK];
        a0 = fmaf(bv.x, h, a0);
        a1 = fmaf(bv.y, h, a1);
        a2 = fmaf(bv.z, h, a2);
        a3 = fmaf(bv.w, h, a3);
    }
    selb[((size_t)b * NK + 0) * ND + d] = __float2bfloat16(a0);
    selb[((size_t)b * NK + 1) * ND + d] = __float2bfloat16(a1);
    selb[((size_t)b * NK + 2) * ND + d] = __float2bfloat16(a2);
    selb[((size_t)b * NK + 3) * ND + d] = __float2bfloat16(a3);
}

// ---------------- K4: big GEMM  C[1024,NPAD2] = selb @ bnv^T ----------------
// Store-bound (256 MB fp32 out). r2/r4 post-mortems: effective write BW pinned at
// ~2 TB/s under both scattered and row-sequential PLAIN stores; r1 NT showed 1.74x
// sector amplification -> theory: scores rows are 64B/16B-MISALIGNED (row start
// float-idx == (1-b) mod 16), so every wave store segment straddles sectors and
// splits into 2 partial transactions on the CU->L2 path, halving store throughput.
// Fix (this round's single change): bounce each row through LDS and re-emit ALIGNED:
// dump acc fragments with aligned ds_write_b128 into a per-wave row buffer; read
// back aligned b128 pairs + wave-uniform dword-rotate (pad in {0..3} per row);
// store 1KB-contiguous 16B-aligned dwordx4 runs; <=3 head/tail floats scalar.
// Values bit-identical to r4. LDS aliased over As/Bs (48 KB unchanged).
__global__ __launch_bounds__(256) void k_gemm(
    const __hip_bfloat16* __restrict__ selb, const __hip_bfloat16* __restrict__ bn,
    float* __restrict__ scores, float* __restrict__ maxs) {
    __shared__ __attribute__((aligned(16))) char pool[49152]; // As 16K | Bs0 16K | Bs1 16K
    __hip_bfloat16* As  = (__hip_bfloat16*)pool;
    __hip_bfloat16* Bs0 = (__hip_bfloat16*)(pool + 16384);
    __hip_bfloat16* Bs1 = (__hip_bfloat16*)(pool + 32768);
    int bm0 = blockIdx.y * 64;
    int nbase = blockIdx.x * GEMM_NSPAN;
    int tid = threadIdx.x;
    int wave = tid >> 6, lane = tid & 63;
    int l16 = lane & 15, quad = lane >> 4;
    int m_loc = wave * 16; // wave owns 16 m-rows x all 512 n
    bool full = (nbase + GEMM_NSPAN) <= NVm1;
    const size_t SC_K = (size_t)NB * NVm1;

    // prologue: stage As (4 glds) + Bs0 (4 glds)
#pragma unroll
    for (int it = 0; it < 4; ++it) {
        int id = it * 256 + tid;
        int row = id >> 4, c = id & 15, gc = c ^ (row & 7);
        gld_lds16((const char*)selb + ((size_t)(bm0 + row) * 16 + gc) * 16,
                  (char*)As + (size_t)(it * 256 + wave * 64) * 16);
    }
#pragma unroll
    for (int it = 0; it < 4; ++it) {
        int id = it * 256 + tid;
        int row = id >> 4, c = id & 15, gc = c ^ (row & 7);
        gld_lds16((const char*)bn + ((size_t)(nbase + row) * 16 + gc) * 16,
                  (char*)Bs0 + (size_t)(it * 256 + wave * 64) * 16);
    }
    __syncthreads();

    const bf16x8* Av = (const bf16x8*)As;
    bf16x8 sf[4];     // selb fragments (B-operand), constant across chunks
#pragma unroll
    for (int kk = 0; kk < 4; ++kk) {
        int row = m_loc + l16, ko = kk * 4 + quad;
        sf[kk] = Av[row * 16 + (ko ^ (row & 7))];
    }

    f32x4 acc[32];    // 128 VGPR accumulator: acc[flat], flat = ch*4+ni
#pragma unroll
    for (int i = 0; i < 32; ++i) acc[i] = (f32x4){0.f, 0.f, 0.f, 0.f};

#pragma unroll
    for (int ch = 0; ch < 8; ++ch) {
        if (ch < 7) {
            int bn0 = nbase + (ch + 1) * 64;
            char* dstB = (char*)(((ch + 1) & 1) ? Bs1 : Bs0);
#pragma unroll
            for (int it = 0; it < 4; ++it) {
                int id = it * 256 + tid;
                int row = id >> 4, c = id & 15, gc = c ^ (row & 7);
                gld_lds16((const char*)bn + ((size_t)(bn0 + row) * 16 + gc) * 16,
                          dstB + (size_t)(it * 256 + wave * 64) * 16);
            }
        }
        const bf16x8* Bv = (const bf16x8*)((ch & 1) ? Bs1 : Bs0);
#pragma unroll
        for (int kk = 0; kk < 4; ++kk) {
            int ko = kk * 4 + quad;
            bf16x8 af[4];
#pragma unroll
            for (int ni = 0; ni < 4; ++ni) {
                int row = ni * 16 + l16;
                af[ni] = Bv[row * 16 + (ko ^ (row & 7))];
            }
#pragma unroll
            for (int ni = 0; ni < 4; ++ni)
                acc[ch * 4 + ni] = __builtin_amdgcn_mfma_f32_16x16x32_bf16(
                    af[ni], sf[kk], acc[ch * 4 + ni], 0, 0, 0);
        }
        __syncthreads(); // prefetch complete + all reads of current Bs done
    }

    // ------- epilogue -------
    // acc[flat][r] = C[n = nbase + flat*16 + quad*4 + r][m], m = bm0 + m_loc + l16.
    if (full) {
        // aligned LDS-bounce: per-wave buffer of 4 rows x 520 floats (8320 B)
        constexpr int BSTR = 520;
        float* wreg = (float*)pool + wave * (4 * BSTR);
        // groups 0..3: scores rows l16 = g*4 + slot; group 4: maxs rows (per b)
        for (int g = 0; g < 5; ++g) {
            if (g < 4) {
                if ((l16 >> 2) == g) {
                    float* dst = wreg + (l16 & 3) * BSTR;
#pragma unroll
                    for (int ni = 0; ni < 32; ++ni)
                        *(f32x4*)&dst[ni * 16 + quad * 4] = acc[ni]; // aligned b128
                }
            } else {
                float* dst = wreg + (l16 >> 2) * BSTR;
                bool act = (l16 & 3) == 0; // l16 in {0,4,8,12} -> slot l16>>2
#pragma unroll
                for (int ni = 0; ni < 32; ++ni) {
                    f32x4 v = acc[ni], w;
#pragma unroll
                    for (int c = 0; c < 4; ++c) {
                        float t = fmaxf(v[c], __shfl_xor(v[c], 1));
                        w[c] = fmaxf(t, __shfl_xor(t, 2));
                    }
                    if (act) *(f32x4*)&dst[ni * 16 + quad * 4] = w;
                }
            }
            // read-back + aligned store (all 64 lanes), 4 rows per group
#pragma unroll
            for (int r = 0; r < 4; ++r) {
                float* p;
                if (g < 4) {
                    int l16r = g * 4 + r;
                    int mr = bm0 + m_loc + l16r;
                    p = scores + (size_t)(l16r & 3) * SC_K + (size_t)(mr >> 2) * NVm1 + nbase;
                } else {
                    int mr = bm0 + m_loc + r * 4;
                    p = maxs + (size_t)(mr >> 2) * NVm1 + nbase;
                }
                const float* src = wreg + r * BSTR;
                size_t fi = ((size_t)(uintptr_t)p) >> 2;   // float index of run start
                int pad = (int)((4 - (fi & 3)) & 3);       // wave-uniform
                float* q = p + pad;                        // 16B-aligned
                int P = (512 - pad) >> 2;                  // aligned piece count
#pragma unroll
                for (int j = 0; j < 2; ++j) {
                    int pc = j * 64 + lane;                // piece index (consec lanes)
                    f32x4 A = *(const f32x4*)&src[4 * pc];
                    f32x4 B = *(const f32x4*)&src[4 * pc + 4]; // in-bounds (BSTR=520)
                    f32x4 o;
                    if (pad == 0)      o = A;
                    else if (pad == 1) o = (f32x4){A[1], A[2], A[3], B[0]};
                    else if (pad == 2) o = (f32x4){A[2], A[3], B[0], B[1]};
                    else               o = (f32x4){A[3], B[0], B[1], B[2]};
                    if (pc < P) *(f32x4*)&q[4 * pc] = o;   // 16B-aligned dwordx4
                }
                // head (pad floats) + tail ((512-pad)&3 floats) scalar
                if (lane < pad) p[lane] = src[lane];
                int t = lane - 4;
                int T = (512 - pad) & 3;
                if (t >= 0 && t < T) {
                    int idx = pad + 4 * P + t;
                    p[idx] = src[idx];
                }
            }
        }
    } else {
        // edge block: old guarded scalar path
        int m = bm0 + m_loc + l16;
        float* srow = scores + (size_t)(l16 & 3) * SC_K + (size_t)(m >> 2) * NVm1;
        float* mrow = maxs + (size_t)(m >> 2) * NVm1;
#pragma unroll
        for (int ni = 0; ni < 32; ++ni) {
            int n0 = nbase + ni * 16 + quad * 4;
            f32x4 v = acc[ni];
            f32x4 w;
#pragma unroll
            for (int c = 0; c < 4; ++c) {
                float t = fmaxf(v[c], __shfl_xor(v[c], 1));
                w[c] = fmaxf(t, __shfl_xor(t, 2));
            }
#pragma unroll
            for (int c = 0; c < 4; ++c) {
                if (n0 + c < NVm1) {
                    srow[n0 + c] = v[c];
                    if ((l16 & 3) == 0) mrow[n0 + c] = w[c];
                }
            }
        }
    }
}

extern "C" void kernel_launch(void* const* d_in, const int* in_sizes, int n_in,
                              void* d_out, int out_size, void* d_ws, size_t ws_size,
                              hipStream_t stream) {
    const float* hidden  = (const float*)d_in[0];
    const int*   mask    = (const int*)d_in[1];
    const float* pos_emb = (const float*)d_in[2];
    const float* w1      = (const float*)d_in[3];
    const float* w2      = (const float*)d_in[4];
    const float* glu1_w  = (const float*)d_in[5];
    const float* glu1_b  = (const float*)d_in[6];
    const float* att_w1  = (const float*)d_in[7];
    const float* att_w2  = (const float*)d_in[8];
    const float* att_v   = (const float*)d_in[9];
    const float* emb     = (const float*)d_in[10];

    float* out      = (float*)d_out;
    float* max_out  = out;                                   // [B, NVm1]
    float* loss_out = out + (size_t)NB * NVm1;               // scalar
    float* scores   = out + (size_t)NB * NVm1 + 1;           // [K, B, NVm1]

    char* w = (char*)d_ws;
    auto alloc = [&](size_t bytes) {
        char* p = w;
        w += (bytes + 255) & ~(size_t)255;
        return p;
    };
    float* posPart = (float*)alloc((size_t)NL * ND * 4);
    float* hsW1    = (float*)alloc((size_t)NB * ND * 4);
    float* betav   = (float*)alloc((size_t)ROWS * NK * 4);
    __hip_bfloat16* XbG     = (__hip_bfloat16*)alloc((size_t)ROWS * ND * 2);
    __hip_bfloat16* w1h_t   = (__hip_bfloat16*)alloc((size_t)ND * ND * 2);
    __hip_bfloat16* attw2_t = (__hip_bfloat16*)alloc((size_t)ND * ND * 2);
    __hip_bfloat16* glu_t   = (__hip_bfloat16*)alloc((size_t)512 * ND * 2);
    __hip_bfloat16* selb    = (__hip_bfloat16*)alloc((size_t)MROWS * ND * 2);
    __hip_bfloat16* bnv     = (__hip_bfloat16*)alloc((size_t)NPAD2 * ND * 2);

    k_prep<<<G_TOT, 256, 0, stream>>>(hidden, mask, pos_emb, w1, att_w1, att_w2, glu1_w,
                                      emb, hsW1, posPart, XbG, w1h_t, attw2_t, glu_t,
                                      bnv, loss_out);
    k_mega<<<ROWS / MR, 256, 0, stream>>>(XbG, w1h_t, attw2_t, glu_t, hsW1,
                                          att_v, posPart, glu1_b, w2, mask, betav);
    k_loss<<<NB, 64, 0, stream>>>(betav, mask, loss_out);
    k_select<<<NB / 2, 256, 0, stream>>>(betav, hidden, selb);
    k_gemm<<<dim3(NPAD2 / GEMM_NSPAN, MROWS / 64), 256, 0, stream>>>(selb, bnv, scores, max_out);
}

// Round 6
// 420.415 us; speedup vs baseline: 1.0797x; 1.0797x over previous
//
#include <hip/hip_runtime.h>
#include <hip/hip_bf16.h>
#include <math.h>

// Problem constants
constexpr int NB = 256;      // batch
constexpr int NL = 50;       // seq len
constexpr int ND = 128;      // dim
constexpr int NK = 4;        // interests
constexpr int NVm1 = 49999;  // V-1
constexpr int NPAD2 = 50176; // N padded to 392*128
constexpr int ROWS = NB * NL;   // 12800
constexpr int MROWS = NB * NK;  // 1024 (rows of select, b-major: row = b*4+k)
constexpr int GEMM_NSPAN = 512; // n cols per block in big GEMM (8 chunks of 64)
constexpr int NWIN = NPAD2 / GEMM_NSPAN; // 98 n-windows
constexpr int MR = 64;          // rows per mega block

// prep kernel block ranges
constexpr int G_BN  = NPAD2 / 8;  // 6272 bnorm (8 rows/blk, float4 per thread)
constexpr int G_HW  = NB / 2;     // 128 hsW1 = (masked-mean hidden) @ att_w1 (2 b/blk)
constexpr int G_PP  = NL / 2;     // 25 posPart (2 rows/blk)
constexpr int G_XB  = ROWS * ND / 2048; // 800 Xb cast
constexpr int G_W1T = ND * ND / 256;    // 64
constexpr int G_AWT = ND * ND / 256;    // 64
constexpr int G_GLT = ND * 512 / 256;   // 256
constexpr int G_TOT = G_BN + G_HW + G_PP + G_XB + G_W1T + G_AWT + G_GLT;

typedef __bf16 bf16x8 __attribute__((ext_vector_type(8)));
typedef float f32x4 __attribute__((ext_vector_type(4)));
typedef f32x4 f32x4u __attribute__((aligned(4))); // align-4 vector (scores rows are not 16B-aligned)

__device__ __forceinline__ float sigm_fast(float x) { return 1.0f / (1.0f + __expf(-x)); }
__device__ __forceinline__ float sigm_prec(float x) { return 1.0f / (1.0f + expf(-x)); }
__device__ __forceinline__ float fast_tanh(float x) {
    float xc = fminf(fmaxf(x, -15.f), 15.f);
    float e = __expf(2.f * xc);
    return (e - 1.f) / (e + 1.f);
}

__device__ __forceinline__ void gld_lds16(const void* g, void* l) {
    __builtin_amdgcn_global_load_lds(
        (const __attribute__((address_space(1))) void*)g,
        (__attribute__((address_space(3))) void*)l, 16, 0, 0);
}

// ---------------- K0: prep — bnorm, hsW1, posPart, Xb cast, weight transposes ----------------
__global__ __launch_bounds__(256) void k_prep(
    const float* __restrict__ hidden, const int* __restrict__ mask,
    const float* __restrict__ pos_emb, const float* __restrict__ w1,
    const float* __restrict__ att_w1, const float* __restrict__ att_w2,
    const float* __restrict__ glu1_w, const float* __restrict__ emb,
    float* __restrict__ hsW1, float* __restrict__ posPart,
    __hip_bfloat16* __restrict__ XbG, __hip_bfloat16* __restrict__ w1h_t,
    __hip_bfloat16* __restrict__ attw2_t, __hip_bfloat16* __restrict__ glu_t,
    __hip_bfloat16* __restrict__ bnv, float* __restrict__ loss_out) {
    __shared__ float sPP[2 * ND];
    int blk = blockIdx.x, tid = threadIdx.x;
    if (blk < G_BN) {
        int v = blk * 8 + (tid >> 5);
        int j = (tid & 31) << 2;
        float4 x = make_float4(0.f, 0.f, 0.f, 0.f);
        if (v < NVm1) x = *(const float4*)&emb[((size_t)v + 1) * ND + j];
        float ss = x.x * x.x + x.y * x.y + x.z * x.z + x.w * x.w;
#pragma unroll
        for (int off = 16; off >= 1; off >>= 1) ss += __shfl_xor(ss, off);
        float rn = 1.f / fmaxf(sqrtf(ss), 1e-12f);
        union { ushort4 u4; __hip_bfloat16 h[4]; } o;
        o.h[0] = __float2bfloat16(x.x * rn);
        o.h[1] = __float2bfloat16(x.y * rn);
        o.h[2] = __float2bfloat16(x.z * rn);
        o.h[3] = __float2bfloat16(x.w * rn);
        *(ushort4*)&bnv[(size_t)v * ND + j] = o.u4;
    } else if (blk < G_BN + G_HW) {
        int half = tid >> 7, d = tid & 127;
        int b = (blk - G_BN) * 2 + half;
        float acc = 0.f, msum = 0.f;
        for (int l = 0; l < NL; ++l) {
            float mv = (float)mask[b * NL + l];
            acc += hidden[((size_t)b * NL + l) * ND + d] * mv;
            msum += mv;
        }
        sPP[half * ND + d] = acc / msum;
        __syncthreads();
        float o = 0.f;
#pragma unroll 8
        for (int j = 0; j < ND; ++j) o += sPP[half * ND + j] * att_w1[j * ND + d];
        hsW1[b * ND + d] = o;
        if (blk == G_BN && tid == 0) loss_out[0] = 0.f;
    } else if (blk < G_BN + G_HW + G_PP) {
        int rel = blk - (G_BN + G_HW);
        int rl = tid >> 7, d = tid & 127;
        int r = rel * 2 + rl;
        sPP[rl * ND + d] = pos_emb[r * ND + d];
        __syncthreads();
        float acc = 0.f;
#pragma unroll 8
        for (int j = 0; j < ND; ++j) acc += sPP[rl * ND + j] * w1[j * ND + d];
        posPart[r * ND + d] = acc;
    } else if (blk < G_BN + G_HW + G_PP + G_XB) {
        int rel = blk - (G_BN + G_HW + G_PP);
        size_t base = (size_t)rel * 2048 + (size_t)tid * 8;
        float4 f0 = *(const float4*)&hidden[base];
        float4 f1 = *(const float4*)&hidden[base + 4];
        union { bf16x8 v; __hip_bfloat16 h[8]; } u;
        u.h[0] = __float2bfloat16(f0.x); u.h[1] = __float2bfloat16(f0.y);
        u.h[2] = __float2bfloat16(f0.z); u.h[3] = __float2bfloat16(f0.w);
        u.h[4] = __float2bfloat16(f1.x); u.h[5] = __float2bfloat16(f1.y);
        u.h[6] = __float2bfloat16(f1.z); u.h[7] = __float2bfloat16(f1.w);
        *(bf16x8*)&XbG[base] = u.v;
    } else if (blk < G_BN + G_HW + G_PP + G_XB + G_W1T) {
        int i = (blk - (G_BN + G_HW + G_PP + G_XB)) * 256 + tid;
        int d = i >> 7, j = i & 127;
        w1h_t[d * ND + j] = __float2bfloat16(w1[(ND + j) * ND + d]);
    } else if (blk < G_BN + G_HW + G_PP + G_XB + G_W1T + G_AWT) {
        int i = (blk - (G_BN + G_HW + G_PP + G_XB + G_W1T)) * 256 + tid;
        int d = i >> 7, j = i & 127;
        attw2_t[d * ND + j] = __float2bfloat16(att_w2[j * ND + d]);
    } else {
        int i = (blk - (G_BN + G_HW + G_PP + G_XB + G_W1T + G_AWT)) * 256 + tid;
        int c = i >> 7, j = i & 127;
        glu_t[c * ND + j] = __float2bfloat16(glu1_w[j * 512 + c]);
    }
}

// ---------------- K1: mega — GEMM1(att,nh via MFMA) + alpha + GEMM2(glu) + beta ----------------
__global__ __launch_bounds__(256) void k_mega(
    const __hip_bfloat16* __restrict__ XbG, const __hip_bfloat16* __restrict__ w1h_t,
    const __hip_bfloat16* __restrict__ attw2_t, const __hip_bfloat16* __restrict__ glu_t,
    const float* __restrict__ hsW1, const float* __restrict__ att_v,
    const float* __restrict__ posPart, const float* __restrict__ glu1_b,
    const float* __restrict__ w2, const int* __restrict__ mask,
    float* __restrict__ beta_out) {
    __shared__ __hip_bfloat16 XbS[MR * ND];   // 16 KB swizzled
    __shared__ __hip_bfloat16 WS[ND * ND];    // 32 KB swizzled
    __shared__ __attribute__((aligned(16))) __hip_bfloat16 NHS[MR * 136]; // padded (+8)
    __shared__ float alphaS[MR * NK];
    __shared__ float hsW1S[3 * ND];
    int row0 = blockIdx.x * MR;
    int tid = threadIdx.x;
    int wave = tid >> 6, lane = tid & 63, l16 = lane & 15, quad = lane >> 4;
    int b0 = row0 / NL;

#pragma unroll
    for (int it = 0; it < 4; ++it) {
        int id = it * 256 + tid;
        int row = id >> 4, c = id & 15, gc = c ^ (row & 7);
        gld_lds16((const char*)XbG + ((size_t)(row0 + row) * 16 + gc) * 16,
                  (char*)XbS + (size_t)(it * 256 + wave * 64) * 16);
    }
#pragma unroll
    for (int it = 0; it < 8; ++it) {
        int id = it * 256 + tid;
        int row = id >> 4, c = id & 15, gc = c ^ (row & 7);
        gld_lds16((const char*)attw2_t + ((size_t)row * 16 + gc) * 16,
                  (char*)WS + (size_t)(it * 256 + wave * 64) * 16);
    }
    for (int i = tid; i < 3 * ND; i += 256) {
        int b = b0 + (i >> 7);
        hsW1S[i] = (b < NB) ? hsW1[b * ND + (i & 127)] : 0.f;
    }
    __syncthreads();

    const bf16x8* Xv = (const bf16x8*)XbS;
    const bf16x8* Wv = (const bf16x8*)WS;
    const bf16x8* Nv = (const bf16x8*)NHS; // row stride 17 (136 bf16)
    int arow = wave * 16 + l16;

    f32x4 acc8[8];
    // ---- GEMM1-att ----
#pragma unroll
    for (int ni = 0; ni < 8; ++ni) acc8[ni] = (f32x4){0.f, 0.f, 0.f, 0.f};
#pragma unroll
    for (int kk = 0; kk < 4; ++kk) {
        int ko = kk * 4 + quad;
        bf16x8 af = Xv[arow * 16 + (ko ^ (arow & 7))];
#pragma unroll
        for (int ni = 0; ni < 8; ++ni) {
            int n = ni * 16 + l16;
            bf16x8 bf = Wv[n * 16 + (ko ^ (n & 7))];
            acc8[ni] = __builtin_amdgcn_mfma_f32_16x16x32_bf16(af, bf, acc8[ni], 0, 0, 0);
        }
    }
#pragma unroll
    for (int r = 0; r < 4; ++r) {
        int lrow = wave * 16 + quad * 4 + r;
        int grow = row0 + lrow;
        int bb = grow / NL - b0;
        float a0 = 0.f, a1 = 0.f, a2 = 0.f, a3 = 0.f;
#pragma unroll
        for (int ni = 0; ni < 8; ++ni) {
            int col = ni * 16 + l16;
            float atv = fast_tanh(hsW1S[bb * ND + col] + acc8[ni][r]);
            float4 av = *(const float4*)&att_v[col * 4];
            a0 += atv * av.x; a1 += atv * av.y; a2 += atv * av.z; a3 += atv * av.w;
        }
#pragma unroll
        for (int off = 1; off < 16; off <<= 1) {
            a0 += __shfl_xor(a0, off); a1 += __shfl_xor(a1, off);
            a2 += __shfl_xor(a2, off); a3 += __shfl_xor(a3, off);
        }
        if (l16 == 0) {
            alphaS[lrow * 4 + 0] = sigm_fast(a0);
            alphaS[lrow * 4 + 1] = sigm_fast(a1);
            alphaS[lrow * 4 + 2] = sigm_fast(a2);
            alphaS[lrow * 4 + 3] = sigm_fast(a3);
        }
    }
    __syncthreads(); // WS reads done
#pragma unroll
    for (int it = 0; it < 8; ++it) {
        int id = it * 256 + tid;
        int row = id >> 4, c = id & 15, gc = c ^ (row & 7);
        gld_lds16((const char*)w1h_t + ((size_t)row * 16 + gc) * 16,
                  (char*)WS + (size_t)(it * 256 + wave * 64) * 16);
    }
    __syncthreads();
    // ---- GEMM1-nh ----
#pragma unroll
    for (int ni = 0; ni < 8; ++ni) acc8[ni] = (f32x4){0.f, 0.f, 0.f, 0.f};
#pragma unroll
    for (int kk = 0; kk < 4; ++kk) {
        int ko = kk * 4 + quad;
        bf16x8 af = Xv[arow * 16 + (ko ^ (arow & 7))];
#pragma unroll
        for (int ni = 0; ni < 8; ++ni) {
            int n = ni * 16 + l16;
            bf16x8 bf = Wv[n * 16 + (ko ^ (n & 7))];
            acc8[ni] = __builtin_amdgcn_mfma_f32_16x16x32_bf16(af, bf, acc8[ni], 0, 0, 0);
        }
    }
#pragma unroll
    for (int r = 0; r < 4; ++r) {
        int lrow = wave * 16 + quad * 4 + r;
        int grow = row0 + lrow;
        int l = grow % NL;
#pragma unroll
        for (int ni = 0; ni < 8; ++ni) {
            int col = ni * 16 + l16;
            float nhv = fast_tanh(posPart[l * ND + col] + acc8[ni][r]);
            NHS[lrow * 136 + col] = __float2bfloat16(nhv);
        }
    }
    __syncthreads(); // NHS complete, WS free
    // ---- GEMM2: 4 chunks of 128 cols; chunk ch == k-segment ch ----
    for (int ch = 0; ch < 4; ++ch) {
#pragma unroll
        for (int it = 0; it < 8; ++it) {
            int id = it * 256 + tid;
            int row = id >> 4, c = id & 15, gc = c ^ (row & 7);
            gld_lds16((const char*)glu_t + ((size_t)(ch * ND + row) * 16 + gc) * 16,
                      (char*)WS + (size_t)(it * 256 + wave * 64) * 16);
        }
        __syncthreads();
#pragma unroll
        for (int ni = 0; ni < 8; ++ni) acc8[ni] = (f32x4){0.f, 0.f, 0.f, 0.f};
#pragma unroll
        for (int kk = 0; kk < 4; ++kk) {
            int ko = kk * 4 + quad;
            bf16x8 af = Nv[arow * 17 + ko]; // padded, no swizzle
#pragma unroll
            for (int ni = 0; ni < 8; ++ni) {
                int n = ni * 16 + l16;
                bf16x8 bf = Wv[n * 16 + (ko ^ (n & 7))];
                acc8[ni] = __builtin_amdgcn_mfma_f32_16x16x32_bf16(af, bf, acc8[ni], 0, 0, 0);
            }
        }
#pragma unroll
        for (int r = 0; r < 4; ++r) {
            float s = 0.f;
#pragma unroll
            for (int ni = 0; ni < 8; ++ni) {
                int col = ni * 16 + l16;
                s += sigm_fast(acc8[ni][r] + glu1_b[ch * ND + col]) * w2[col * 4 + ch];
            }
#pragma unroll
            for (int off = 1; off < 16; off <<= 1) s += __shfl_xor(s, off);
            if (l16 == 0) {
                int lrow = wave * 16 + quad * 4 + r;
                int grow = row0 + lrow;
                float a = alphaS[lrow * 4 + ch];
                beta_out[(size_t)grow * 4 + ch] = s * (0.5f + a) * (float)mask[grow];
            }
        }
        __syncthreads();
    }
}

// ---------------- K2: loss (lens inline, atomic accumulate) ----------------
__global__ void k_loss(const float* __restrict__ beta, const int* __restrict__ mask,
                       float* __restrict__ loss_out) {
    int b = blockIdx.x;
    int t = threadIdx.x; // 64
    float mv = (t < NL) ? (float)mask[b * NL + t] : 0.f;
    float msum = mv;
    for (int off = 32; off >= 1; off >>= 1) msum += __shfl_xor(msum, off);
    float lens = msum - 5.0f; // LENGTH=5
    float bk[NK] = {0.f, 0.f, 0.f, 0.f};
    if (t < NL) {
#pragma unroll
        for (int k = 0; k < NK; ++k) bk[k] = beta[((size_t)b * NL + t) * NK + k];
    }
    float nb[NK];
#pragma unroll
    for (int k = 0; k < NK; ++k) {
        float v = bk[k] * bk[k];
        for (int off = 32; off >= 1; off >>= 1) v += __shfl_xor(v, off);
        nb[k] = bk[k] / fmaxf(sqrtf(v), 1e-12f);
    }
    float sim = 0.f;
#pragma unroll
    for (int i = 0; i < NK; ++i) {
#pragma unroll
        for (int j = 0; j < NK; ++j) {
            if (j > i) {
                float p = nb[i] * nb[j];
                for (int off = 32; off >= 1; off >>= 1) p += __shfl_xor(p, off);
                sim += fabsf(p);
            }
        }
    }
    sim *= (2.0f / (NK * (NK - 1)));
    if (t == 0) atomicAdd(loss_out, sigm_prec(sim * lens) * 0.01f); // BETA
}

// ---------------- K3: select -> bf16 (2 b per block) ----------------
__global__ __launch_bounds__(256) void k_select(
    const float* __restrict__ beta, const float* __restrict__ hidden,
    __hip_bfloat16* __restrict__ selb) {
    int b = blockIdx.x * 2 + (threadIdx.x >> 7);
    int d = threadIdx.x & 127;
    float a0 = 0.f, a1 = 0.f, a2 = 0.f, a3 = 0.f;
    for (int l = 0; l < NL; ++l) {
        float h = hidden[((size_t)b * NL + l) * ND + d];
        float4 bv = *(const float4*)&beta[((size_t)b * NL + l) * NK];
        a0 = fmaf(bv.x, h, a0);
        a1 = fmaf(bv.y, h, a1);
        a2 = fmaf(bv.z, h, a2);
        a3 = fmaf(bv.w, h, a3);
    }
    selb[((size_t)b * NK + 0) * ND + d] = __float2bfloat16(a0);
    selb[((size_t)b * NK + 1) * ND + d] = __float2bfloat16(a1);
    selb[((size_t)b * NK + 2) * ND + d] = __float2bfloat16(a2);
    selb[((size_t)b * NK + 3) * ND + d] = __float2bfloat16(a3);
}

// ---------------- K4: big GEMM  C[1024,NPAD2] = selb @ bnv^T ----------------
// Store-bound (256 MB fp32 out). r1-r5 established: store SHAPE at the CU doesn't
// move the ~140us floor (scatter / sequential-2KB / aligned-LDS-bounce all equal;
// NT catastrophic). Surviving theory: r1 FETCH=43MB shows bnv re-fetched ~3.4x from
// HBM (score writes flush LLC) -> DRAM sees fine-grained read/write interleave.
// This round: XCD-AFFINE WINDOW SCHEDULING. 1D grid 1664; block g -> XCD g&7
// (dispatch round-robin heuristic; locality-only, correctness unaffected). Each XCD
// owns a contiguous run of 12-13 n-windows; y-inner ordering makes the 16 y-blocks
// of one window run consecutively on that XCD -> the window's 256KB bnv slice is
// HBM-fetched once, L2-served 15x. Epilogue reverted to r4 sequential-run form.
__global__ __launch_bounds__(256) void k_gemm(
    const __hip_bfloat16* __restrict__ selb, const __hip_bfloat16* __restrict__ bn,
    float* __restrict__ scores, float* __restrict__ maxs) {
    __shared__ __attribute__((aligned(16))) __hip_bfloat16 As[64 * 128];     // 16 KB
    __shared__ __attribute__((aligned(16))) __hip_bfloat16 Bs[2][64 * 128];  // 2x16 KB
    // --- XCD-affine remap: g -> (window wi, y) ---
    int g = blockIdx.x;
    int xcd = g & 7, j = g >> 3;            // per-XCD work index (assumes RR dispatch)
    int nwin = 12 + (xcd < 2 ? 1 : 0);      // 98 = 8*12 + 2
    if (j >= nwin * 16) return;             // idle pad blocks (uniform exit, no barrier yet)
    int wi = xcd * 12 + (xcd < 2 ? xcd : 2) + (j >> 4); // this XCD's window run
    int bm0 = (j & 15) * 64;
    int nbase = wi * GEMM_NSPAN;
    int tid = threadIdx.x;
    int wave = tid >> 6, lane = tid & 63;
    int l16 = lane & 15, quad = lane >> 4;
    int m_loc = wave * 16; // wave owns 16 m-rows x all 512 n
    bool full = (nbase + GEMM_NSPAN) <= NVm1;
    const size_t SC_K = (size_t)NB * NVm1;

    // prologue: stage As (4 glds) + Bs[0] (4 glds)
#pragma unroll
    for (int it = 0; it < 4; ++it) {
        int id = it * 256 + tid;
        int row = id >> 4, c = id & 15, gc = c ^ (row & 7);
        gld_lds16((const char*)selb + ((size_t)(bm0 + row) * 16 + gc) * 16,
                  (char*)As + (size_t)(it * 256 + wave * 64) * 16);
    }
#pragma unroll
    for (int it = 0; it < 4; ++it) {
        int id = it * 256 + tid;
        int row = id >> 4, c = id & 15, gc = c ^ (row & 7);
        gld_lds16((const char*)bn + ((size_t)(nbase + row) * 16 + gc) * 16,
                  (char*)Bs[0] + (size_t)(it * 256 + wave * 64) * 16);
    }
    __syncthreads();

    const bf16x8* Av = (const bf16x8*)As;
    bf16x8 sf[4];     // selb fragments (B-operand), constant across chunks
#pragma unroll
    for (int kk = 0; kk < 4; ++kk) {
        int row = m_loc + l16, ko = kk * 4 + quad;
        sf[kk] = Av[row * 16 + (ko ^ (row & 7))];
    }

    f32x4 acc[32];    // 128 VGPR accumulator: acc[flat], flat = ch*4+ni
#pragma unroll
    for (int i = 0; i < 32; ++i) acc[i] = (f32x4){0.f, 0.f, 0.f, 0.f};

#pragma unroll
    for (int ch = 0; ch < 8; ++ch) {
        if (ch < 7) {
            int bn0 = nbase + (ch + 1) * 64;
#pragma unroll
            for (int it = 0; it < 4; ++it) {
                int id = it * 256 + tid;
                int row = id >> 4, c = id & 15, gc = c ^ (row & 7);
                gld_lds16((const char*)bn + ((size_t)(bn0 + row) * 16 + gc) * 16,
                          (char*)Bs[(ch + 1) & 1] + (size_t)(it * 256 + wave * 64) * 16);
            }
        }
        const bf16x8* Bv = (const bf16x8*)Bs[ch & 1];
#pragma unroll
        for (int kk = 0; kk < 4; ++kk) {
            int ko = kk * 4 + quad;
            bf16x8 af[4];
#pragma unroll
            for (int ni = 0; ni < 4; ++ni) {
                int row = ni * 16 + l16;
                af[ni] = Bv[row * 16 + (ko ^ (row & 7))];
            }
#pragma unroll
            for (int ni = 0; ni < 4; ++ni)
                acc[ch * 4 + ni] = __builtin_amdgcn_mfma_f32_16x16x32_bf16(
                    af[ni], sf[kk], acc[ch * 4 + ni], 0, 0, 0);
        }
        __syncthreads(); // prefetch complete + all reads of current Bs done
    }

    // epilogue (r4 form): lane owns row m = bm0 + m_loc + l16 -> k = l16&3, b = m>>2.
    // acc[flat][r] = C[n = nbase + flat*16 + quad*4 + r][m]. 32 sequential align-4
    // dwordx4 stores cover the row's full 2 KB n-span.
    int m = bm0 + m_loc + l16;
    float* srow = scores + (size_t)(l16 & 3) * SC_K + (size_t)(m >> 2) * NVm1;
    float* mrow = maxs + (size_t)(m >> 2) * NVm1;
    if (full) {
#pragma unroll
        for (int ni = 0; ni < 32; ++ni) {
            int n0 = nbase + ni * 16 + quad * 4;
            f32x4 v = acc[ni];
            *(f32x4u*)&srow[n0] = v;
            f32x4 w;
#pragma unroll
            for (int c = 0; c < 4; ++c) {
                float t = fmaxf(v[c], __shfl_xor(v[c], 1));
                w[c] = fmaxf(t, __shfl_xor(t, 2));
            }
            if ((l16 & 3) == 0) *(f32x4u*)&mrow[n0] = w;
        }
    } else {
#pragma unroll
        for (int ni = 0; ni < 32; ++ni) {
            int n0 = nbase + ni * 16 + quad * 4;
            f32x4 v = acc[ni];
            f32x4 w;
#pragma unroll
            for (int c = 0; c < 4; ++c) {
                float t = fmaxf(v[c], __shfl_xor(v[c], 1));
                w[c] = fmaxf(t, __shfl_xor(t, 2));
            }
#pragma unroll
            for (int c = 0; c < 4; ++c) {
                if (n0 + c < NVm1) {
                    srow[n0 + c] = v[c];
                    if ((l16 & 3) == 0) mrow[n0 + c] = w[c];
                }
            }
        }
    }
}

extern "C" void kernel_launch(void* const* d_in, const int* in_sizes, int n_in,
                              void* d_out, int out_size, void* d_ws, size_t ws_size,
                              hipStream_t stream) {
    const float* hidden  = (const float*)d_in[0];
    const int*   mask    = (const int*)d_in[1];
    const float* pos_emb = (const float*)d_in[2];
    const float* w1      = (const float*)d_in[3];
    const float* w2      = (const float*)d_in[4];
    const float* glu1_w  = (const float*)d_in[5];
    const float* glu1_b  = (const float*)d_in[6];
    const float* att_w1  = (const float*)d_in[7];
    const float* att_w2  = (const float*)d_in[8];
    const float* att_v   = (const float*)d_in[9];
    const float* emb     = (const float*)d_in[10];

    float* out      = (float*)d_out;
    float* max_out  = out;                                   // [B, NVm1]
    float* loss_out = out + (size_t)NB * NVm1;               // scalar
    float* scores   = out + (size_t)NB * NVm1 + 1;           // [K, B, NVm1]

    char* w = (char*)d_ws;
    auto alloc = [&](size_t bytes) {
        char* p = w;
        w += (bytes + 255) & ~(size_t)255;
        return p;
    };
    float* posPart = (float*)alloc((size_t)NL * ND * 4);
    float* hsW1    = (float*)alloc((size_t)NB * ND * 4);
    float* betav   = (float*)alloc((size_t)ROWS * NK * 4);
    __hip_bfloat16* XbG     = (__hip_bfloat16*)alloc((size_t)ROWS * ND * 2);
    __hip_bfloat16* w1h_t   = (__hip_bfloat16*)alloc((size_t)ND * ND * 2);
    __hip_bfloat16* attw2_t = (__hip_bfloat16*)alloc((size_t)ND * ND * 2);
    __hip_bfloat16* glu_t   = (__hip_bfloat16*)alloc((size_t)512 * ND * 2);
    __hip_bfloat16* selb    = (__hip_bfloat16*)alloc((size_t)MROWS * ND * 2);
    __hip_bfloat16* bnv     = (__hip_bfloat16*)alloc((size_t)NPAD2 * ND * 2);

    k_prep<<<G_TOT, 256, 0, stream>>>(hidden, mask, pos_emb, w1, att_w1, att_w2, glu1_w,
                                      emb, hsW1, posPart, XbG, w1h_t, attw2_t, glu_t,
                                      bnv, loss_out);
    k_mega<<<ROWS / MR, 256, 0, stream>>>(XbG, w1h_t, attw2_t, glu_t, hsW1,
                                          att_v, posPart, glu1_b, w2, mask, betav);
    k_loss<<<NB, 64, 0, stream>>>(betav, mask, loss_out);
    k_select<<<NB / 2, 256, 0, stream>>>(betav, hidden, selb);
    // 1664 = 8 XCDs x 208 slots (13 windows x 16 y); XCDs 2..7 idle last 16 slots
    k_gemm<<<1664, 256, 0, stream>>>(selb, bnv, scores, max_out);
}

// Round 7
// 415.061 us; speedup vs baseline: 1.0936x; 1.0129x over previous
//
#include <hip/hip_runtime.h>
#include <hip/hip_bf16.h>
#include <math.h>

// Problem constants
constexpr int NB = 256;      // batch
constexpr int NL = 50;       // seq len
constexpr int ND = 128;      // dim
constexpr int NK = 4;        // interests
constexpr int NVm1 = 49999;  // V-1
constexpr int NPAD2 = 50176; // N padded to 392*128
constexpr int ROWS = NB * NL;   // 12800
constexpr int MROWS = NB * NK;  // 1024 (rows of select, b-major: row = b*4+k)
constexpr int GEMM_NSPAN = 512; // n cols per block in big GEMM (8 chunks of 64)

// prep kernel block ranges
constexpr int G_BN  = NPAD2 / 8;  // 6272 bnorm (8 rows/blk, float4 per thread)
constexpr int G_HW  = NB / 2;     // 128 hsW1 = (masked-mean hidden) @ att_w1 (2 b/blk)
constexpr int G_PP  = NL / 2;     // 25 posPart (2 rows/blk)
constexpr int G_XB  = ROWS * ND / 2048; // 800 Xb cast
constexpr int G_W1T = ND * ND / 256;    // 64
constexpr int G_AWT = ND * ND / 256;    // 64
constexpr int G_GLT = ND * 512 / 256;   // 256
constexpr int G_TOT = G_BN + G_HW + G_PP + G_XB + G_W1T + G_AWT + G_GLT;

typedef __bf16 bf16x8 __attribute__((ext_vector_type(8)));
typedef float f32x4 __attribute__((ext_vector_type(4)));
typedef f32x4 f32x4u __attribute__((aligned(4))); // align-4 vector (scores rows are not 16B-aligned)

__device__ __forceinline__ float sigm_fast(float x) { return 1.0f / (1.0f + __expf(-x)); }
__device__ __forceinline__ float sigm_prec(float x) { return 1.0f / (1.0f + expf(-x)); }
__device__ __forceinline__ float fast_tanh(float x) {
    float xc = fminf(fmaxf(x, -15.f), 15.f); // also squashes NaN garbage from pad rows to -15
    float e = __expf(2.f * xc);
    return (e - 1.f) / (e + 1.f);
}

__device__ __forceinline__ void gld_lds16(const void* g, void* l) {
    __builtin_amdgcn_global_load_lds(
        (const __attribute__((address_space(1))) void*)g,
        (__attribute__((address_space(3))) void*)l, 16, 0, 0);
}

// ---------------- K0: prep — bnorm, hsW1, posPart, Xb cast, weight transposes ----------------
__global__ __launch_bounds__(256) void k_prep(
    const float* __restrict__ hidden, const int* __restrict__ mask,
    const float* __restrict__ pos_emb, const float* __restrict__ w1,
    const float* __restrict__ att_w1, const float* __restrict__ att_w2,
    const float* __restrict__ glu1_w, const float* __restrict__ emb,
    float* __restrict__ hsW1, float* __restrict__ posPart,
    __hip_bfloat16* __restrict__ XbG, __hip_bfloat16* __restrict__ w1h_t,
    __hip_bfloat16* __restrict__ attw2_t, __hip_bfloat16* __restrict__ glu_t,
    __hip_bfloat16* __restrict__ bnv, float* __restrict__ loss_out) {
    __shared__ float sPP[2 * ND];
    int blk = blockIdx.x, tid = threadIdx.x;
    if (blk < G_BN) {
        int v = blk * 8 + (tid >> 5);
        int j = (tid & 31) << 2;
        float4 x = make_float4(0.f, 0.f, 0.f, 0.f);
        if (v < NVm1) x = *(const float4*)&emb[((size_t)v + 1) * ND + j];
        float ss = x.x * x.x + x.y * x.y + x.z * x.z + x.w * x.w;
#pragma unroll
        for (int off = 16; off >= 1; off >>= 1) ss += __shfl_xor(ss, off);
        float rn = 1.f / fmaxf(sqrtf(ss), 1e-12f);
        union { ushort4 u4; __hip_bfloat16 h[4]; } o;
        o.h[0] = __float2bfloat16(x.x * rn);
        o.h[1] = __float2bfloat16(x.y * rn);
        o.h[2] = __float2bfloat16(x.z * rn);
        o.h[3] = __float2bfloat16(x.w * rn);
        *(ushort4*)&bnv[(size_t)v * ND + j] = o.u4;
    } else if (blk < G_BN + G_HW) {
        int half = tid >> 7, d = tid & 127;
        int b = (blk - G_BN) * 2 + half;
        float acc = 0.f, msum = 0.f;
        for (int l = 0; l < NL; ++l) {
            float mv = (float)mask[b * NL + l];
            acc += hidden[((size_t)b * NL + l) * ND + d] * mv;
            msum += mv;
        }
        sPP[half * ND + d] = acc / msum;
        __syncthreads();
        float o = 0.f;
#pragma unroll 8
        for (int j = 0; j < ND; ++j) o += sPP[half * ND + j] * att_w1[j * ND + d];
        hsW1[b * ND + d] = o;
        if (blk == G_BN && tid == 0) loss_out[0] = 0.f;
    } else if (blk < G_BN + G_HW + G_PP) {
        int rel = blk - (G_BN + G_HW);
        int rl = tid >> 7, d = tid & 127;
        int r = rel * 2 + rl;
        sPP[rl * ND + d] = pos_emb[r * ND + d];
        __syncthreads();
        float acc = 0.f;
#pragma unroll 8
        for (int j = 0; j < ND; ++j) acc += sPP[rl * ND + j] * w1[j * ND + d];
        posPart[r * ND + d] = acc;
    } else if (blk < G_BN + G_HW + G_PP + G_XB) {
        int rel = blk - (G_BN + G_HW + G_PP);
        size_t base = (size_t)rel * 2048 + (size_t)tid * 8;
        float4 f0 = *(const float4*)&hidden[base];
        float4 f1 = *(const float4*)&hidden[base + 4];
        union { bf16x8 v; __hip_bfloat16 h[8]; } u;
        u.h[0] = __float2bfloat16(f0.x); u.h[1] = __float2bfloat16(f0.y);
        u.h[2] = __float2bfloat16(f0.z); u.h[3] = __float2bfloat16(f0.w);
        u.h[4] = __float2bfloat16(f1.x); u.h[5] = __float2bfloat16(f1.y);
        u.h[6] = __float2bfloat16(f1.z); u.h[7] = __float2bfloat16(f1.w);
        *(bf16x8*)&XbG[base] = u.v;
    } else if (blk < G_BN + G_HW + G_PP + G_XB + G_W1T) {
        int i = (blk - (G_BN + G_HW + G_PP + G_XB)) * 256 + tid;
        int d = i >> 7, j = i & 127;
        w1h_t[d * ND + j] = __float2bfloat16(w1[(ND + j) * ND + d]);
    } else if (blk < G_BN + G_HW + G_PP + G_XB + G_W1T + G_AWT) {
        int i = (blk - (G_BN + G_HW + G_PP + G_XB + G_W1T)) * 256 + tid;
        int d = i >> 7, j = i & 127;
        attw2_t[d * ND + j] = __float2bfloat16(att_w2[j * ND + d]);
    } else {
        int i = (blk - (G_BN + G_HW + G_PP + G_XB + G_W1T + G_AWT)) * 256 + tid;
        int c = i >> 7, j = i & 127;
        glu_t[c * ND + j] = __float2bfloat16(glu1_w[j * 512 + c]);
    }
}

// ---------------- K1: megaf — per-batch fused mega + loss + select ----------------
// Block b owns batch element b: rows b*50..b*50+49, padded to 64 MFMA rows (pad rows
// compute clamped garbage, never stored). beta lives in LDS only (no betav round-trip);
// loss (wave 0 shuffle reduce) and select (all threads, half-l split + LDS combine)
// run in the same block. Kills 2 launches + one HBM round-trip vs r6's 5-kernel chain.
__global__ __launch_bounds__(256) void k_megaf(
    const __hip_bfloat16* __restrict__ XbG, const __hip_bfloat16* __restrict__ w1h_t,
    const __hip_bfloat16* __restrict__ attw2_t, const __hip_bfloat16* __restrict__ glu_t,
    const float* __restrict__ hsW1, const float* __restrict__ att_v,
    const float* __restrict__ posPart, const float* __restrict__ glu1_b,
    const float* __restrict__ w2, const int* __restrict__ mask,
    const float* __restrict__ hidden, __hip_bfloat16* __restrict__ selb,
    float* __restrict__ loss_out) {
    __shared__ __hip_bfloat16 XbS[64 * ND];   // 16 KB swizzled
    __shared__ __hip_bfloat16 WS[ND * ND];    // 32 KB swizzled
    __shared__ __attribute__((aligned(16))) __hip_bfloat16 NHS[64 * 136]; // padded (+8)
    __shared__ float alphaS[64 * NK];
    __shared__ float hsW1S[ND];
    __shared__ float betaS[64 * NK];
    __shared__ float selH[2][NK][ND];         // 4 KB half-l select partials
    int b = blockIdx.x;
    int row0 = b * NL;
    int tid = threadIdx.x;
    int wave = tid >> 6, lane = tid & 63, l16 = lane & 15, quad = lane >> 4;

#pragma unroll
    for (int it = 0; it < 4; ++it) {
        int id = it * 256 + tid;
        int row = id >> 4, c = id & 15, gc = c ^ (row & 7);
        gld_lds16((const char*)XbG + ((size_t)(row0 + row) * 16 + gc) * 16,
                  (char*)XbS + (size_t)(it * 256 + wave * 64) * 16);
    }
#pragma unroll
    for (int it = 0; it < 8; ++it) {
        int id = it * 256 + tid;
        int row = id >> 4, c = id & 15, gc = c ^ (row & 7);
        gld_lds16((const char*)attw2_t + ((size_t)row * 16 + gc) * 16,
                  (char*)WS + (size_t)(it * 256 + wave * 64) * 16);
    }
    if (tid < ND) hsW1S[tid] = hsW1[b * ND + tid];
    __syncthreads();

    const bf16x8* Xv = (const bf16x8*)XbS;
    const bf16x8* Wv = (const bf16x8*)WS;
    const bf16x8* Nv = (const bf16x8*)NHS; // row stride 17 (136 bf16)
    int arow = wave * 16 + l16;

    f32x4 acc8[8];
    // ---- GEMM1-att ----
#pragma unroll
    for (int ni = 0; ni < 8; ++ni) acc8[ni] = (f32x4){0.f, 0.f, 0.f, 0.f};
#pragma unroll
    for (int kk = 0; kk < 4; ++kk) {
        int ko = kk * 4 + quad;
        bf16x8 af = Xv[arow * 16 + (ko ^ (arow & 7))];
#pragma unroll
        for (int ni = 0; ni < 8; ++ni) {
            int n = ni * 16 + l16;
            bf16x8 bf = Wv[n * 16 + (ko ^ (n & 7))];
            acc8[ni] = __builtin_amdgcn_mfma_f32_16x16x32_bf16(af, bf, acc8[ni], 0, 0, 0);
        }
    }
#pragma unroll
    for (int r = 0; r < 4; ++r) {
        int lrow = wave * 16 + quad * 4 + r;
        float a0 = 0.f, a1 = 0.f, a2 = 0.f, a3 = 0.f;
#pragma unroll
        for (int ni = 0; ni < 8; ++ni) {
            int col = ni * 16 + l16;
            float atv = fast_tanh(hsW1S[col] + acc8[ni][r]);
            float4 av = *(const float4*)&att_v[col * 4];
            a0 += atv * av.x; a1 += atv * av.y; a2 += atv * av.z; a3 += atv * av.w;
        }
#pragma unroll
        for (int off = 1; off < 16; off <<= 1) {
            a0 += __shfl_xor(a0, off); a1 += __shfl_xor(a1, off);
            a2 += __shfl_xor(a2, off); a3 += __shfl_xor(a3, off);
        }
        if (l16 == 0) {
            alphaS[lrow * 4 + 0] = sigm_fast(a0);
            alphaS[lrow * 4 + 1] = sigm_fast(a1);
            alphaS[lrow * 4 + 2] = sigm_fast(a2);
            alphaS[lrow * 4 + 3] = sigm_fast(a3);
        }
    }
    __syncthreads(); // WS reads done
#pragma unroll
    for (int it = 0; it < 8; ++it) {
        int id = it * 256 + tid;
        int row = id >> 4, c = id & 15, gc = c ^ (row & 7);
        gld_lds16((const char*)w1h_t + ((size_t)row * 16 + gc) * 16,
                  (char*)WS + (size_t)(it * 256 + wave * 64) * 16);
    }
    __syncthreads();
    // ---- GEMM1-nh ----
#pragma unroll
    for (int ni = 0; ni < 8; ++ni) acc8[ni] = (f32x4){0.f, 0.f, 0.f, 0.f};
#pragma unroll
    for (int kk = 0; kk < 4; ++kk) {
        int ko = kk * 4 + quad;
        bf16x8 af = Xv[arow * 16 + (ko ^ (arow & 7))];
#pragma unroll
        for (int ni = 0; ni < 8; ++ni) {
            int n = ni * 16 + l16;
            bf16x8 bf = Wv[n * 16 + (ko ^ (n & 7))];
            acc8[ni] = __builtin_amdgcn_mfma_f32_16x16x32_bf16(af, bf, acc8[ni], 0, 0, 0);
        }
    }
#pragma unroll
    for (int r = 0; r < 4; ++r) {
        int lrow = wave * 16 + quad * 4 + r; // l == lrow (one b per block); pad rows read
#pragma unroll                               // padded posPart (clamped in fast_tanh)
        for (int ni = 0; ni < 8; ++ni) {
            int col = ni * 16 + l16;
            float nhv = fast_tanh(posPart[lrow * ND + col] + acc8[ni][r]);
            NHS[lrow * 136 + col] = __float2bfloat16(nhv);
        }
    }
    __syncthreads(); // NHS complete, WS free
    // ---- GEMM2: 4 chunks of 128 cols; chunk ch == k-segment ch ----
    for (int ch = 0; ch < 4; ++ch) {
#pragma unroll
        for (int it = 0; it < 8; ++it) {
            int id = it * 256 + tid;
            int row = id >> 4, c = id & 15, gc = c ^ (row & 7);
            gld_lds16((const char*)glu_t + ((size_t)(ch * ND + row) * 16 + gc) * 16,
                      (char*)WS + (size_t)(it * 256 + wave * 64) * 16);
        }
        __syncthreads();
#pragma unroll
        for (int ni = 0; ni < 8; ++ni) acc8[ni] = (f32x4){0.f, 0.f, 0.f, 0.f};
#pragma unroll
        for (int kk = 0; kk < 4; ++kk) {
            int ko = kk * 4 + quad;
            bf16x8 af = Nv[arow * 17 + ko]; // padded, no swizzle
#pragma unroll
            for (int ni = 0; ni < 8; ++ni) {
                int n = ni * 16 + l16;
                bf16x8 bf = Wv[n * 16 + (ko ^ (n & 7))];
                acc8[ni] = __builtin_amdgcn_mfma_f32_16x16x32_bf16(af, bf, acc8[ni], 0, 0, 0);
            }
        }
#pragma unroll
        for (int r = 0; r < 4; ++r) {
            float s = 0.f;
#pragma unroll
            for (int ni = 0; ni < 8; ++ni) {
                int col = ni * 16 + l16;
                s += sigm_fast(acc8[ni][r] + glu1_b[ch * ND + col]) * w2[col * 4 + ch];
            }
#pragma unroll
            for (int off = 1; off < 16; off <<= 1) s += __shfl_xor(s, off);
            if (l16 == 0) {
                int lrow = wave * 16 + quad * 4 + r;
                float mval = (lrow < NL) ? (float)mask[row0 + lrow] : 0.f;
                betaS[lrow * 4 + ch] = s * (0.5f + alphaS[lrow * 4 + ch]) * mval;
            }
        }
        __syncthreads(); // betaS(ch) visible; WS reads done
    }

    // ---- select: all 256 threads, half-l split, f32 hidden reads ----
    {
        int d = tid & 127, h = tid >> 7;
        float a0 = 0.f, a1 = 0.f, a2 = 0.f, a3 = 0.f;
        for (int l = h * 25; l < h * 25 + 25; ++l) {
            float hv = hidden[((size_t)row0 + l) * ND + d];
            a0 = fmaf(betaS[l * 4 + 0], hv, a0);
            a1 = fmaf(betaS[l * 4 + 1], hv, a1);
            a2 = fmaf(betaS[l * 4 + 2], hv, a2);
            a3 = fmaf(betaS[l * 4 + 3], hv, a3);
        }
        selH[h][0][d] = a0; selH[h][1][d] = a1;
        selH[h][2][d] = a2; selH[h][3][d] = a3;
    }
    __syncthreads();
    if (tid < ND) {
#pragma unroll
        for (int k = 0; k < NK; ++k)
            selb[((size_t)b * NK + k) * ND + tid] =
                __float2bfloat16(selH[0][k][tid] + selH[1][k][tid]);
    }

    // ---- loss: wave 0 only (64 lanes, shuffle reduce over l) ----
    if (tid < 64) {
        int t = tid;
        float mv = (t < NL) ? (float)mask[row0 + t] : 0.f;
        float msum = mv;
        for (int off = 32; off >= 1; off >>= 1) msum += __shfl_xor(msum, off);
        float lens = msum - 5.0f; // LENGTH=5
        float bk[NK] = {0.f, 0.f, 0.f, 0.f};
        if (t < NL) {
#pragma unroll
            for (int k = 0; k < NK; ++k) bk[k] = betaS[t * 4 + k];
        }
        float nb[NK];
#pragma unroll
        for (int k = 0; k < NK; ++k) {
            float v = bk[k] * bk[k];
            for (int off = 32; off >= 1; off >>= 1) v += __shfl_xor(v, off);
            nb[k] = bk[k] / fmaxf(sqrtf(v), 1e-12f);
        }
        float sim = 0.f;
#pragma unroll
        for (int i = 0; i < NK; ++i) {
#pragma unroll
            for (int j = 0; j < NK; ++j) {
                if (j > i) {
                    float p = nb[i] * nb[j];
                    for (int off = 32; off >= 1; off >>= 1) p += __shfl_xor(p, off);
                    sim += fabsf(p);
                }
            }
        }
        sim *= (2.0f / (NK * (NK - 1)));
        if (t == 0) atomicAdd(loss_out, sigm_prec(sim * lens) * 0.01f); // BETA
    }
}

// ---------------- K4: big GEMM  C[1024,NPAD2] = selb @ bnv^T (r4 form) ----------------
// Store-bound (307 MB fp32 out incl. maxs). r0-r6: five store-pattern variants all
// land at ~140us (~2.2 TB/s effective) -> treated as the chip-level wall for this
// scattered-footprint write mix. Keep the best/simplest: 64m x 512n per block,
// swapped mfma -> lane owns one output row; zero stores in K-loop; epilogue writes
// each row's 2KB as 32 sequential align-4 dwordx4. XCD remap removed (neutral, r6).
__global__ __launch_bounds__(256) void k_gemm(
    const __hip_bfloat16* __restrict__ selb, const __hip_bfloat16* __restrict__ bn,
    float* __restrict__ scores, float* __restrict__ maxs) {
    __shared__ __attribute__((aligned(16))) __hip_bfloat16 As[64 * 128];     // 16 KB
    __shared__ __attribute__((aligned(16))) __hip_bfloat16 Bs[2][64 * 128];  // 2x16 KB
    int bm0 = blockIdx.y * 64;
    int nbase = blockIdx.x * GEMM_NSPAN;
    int tid = threadIdx.x;
    int wave = tid >> 6, lane = tid & 63;
    int l16 = lane & 15, quad = lane >> 4;
    int m_loc = wave * 16; // wave owns 16 m-rows x all 512 n
    bool full = (nbase + GEMM_NSPAN) <= NVm1;
    const size_t SC_K = (size_t)NB * NVm1;

#pragma unroll
    for (int it = 0; it < 4; ++it) {
        int id = it * 256 + tid;
        int row = id >> 4, c = id & 15, gc = c ^ (row & 7);
        gld_lds16((const char*)selb + ((size_t)(bm0 + row) * 16 + gc) * 16,
                  (char*)As + (size_t)(it * 256 + wave * 64) * 16);
    }
#pragma unroll
    for (int it = 0; it < 4; ++it) {
        int id = it * 256 + tid;
        int row = id >> 4, c = id & 15, gc = c ^ (row & 7);
        gld_lds16((const char*)bn + ((size_t)(nbase + row) * 16 + gc) * 16,
                  (char*)Bs[0] + (size_t)(it * 256 + wave * 64) * 16);
    }
    __syncthreads();

    const bf16x8* Av = (const bf16x8*)As;
    bf16x8 sf[4];     // selb fragments (B-operand), constant across chunks
#pragma unroll
    for (int kk = 0; kk < 4; ++kk) {
        int row = m_loc + l16, ko = kk * 4 + quad;
        sf[kk] = Av[row * 16 + (ko ^ (row & 7))];
    }

    f32x4 acc[32];    // 128 VGPR accumulator: acc[flat], flat = ch*4+ni
#pragma unroll
    for (int i = 0; i < 32; ++i) acc[i] = (f32x4){0.f, 0.f, 0.f, 0.f};

#pragma unroll
    for (int ch = 0; ch < 8; ++ch) {
        if (ch < 7) {
            int bn0 = nbase + (ch + 1) * 64;
#pragma unroll
            for (int it = 0; it < 4; ++it) {
                int id = it * 256 + tid;
                int row = id >> 4, c = id & 15, gc = c ^ (row & 7);
                gld_lds16((const char*)bn + ((size_t)(bn0 + row) * 16 + gc) * 16,
                          (char*)Bs[(ch + 1) & 1] + (size_t)(it * 256 + wave * 64) * 16);
            }
        }
        const bf16x8* Bv = (const bf16x8*)Bs[ch & 1];
#pragma unroll
        for (int kk = 0; kk < 4; ++kk) {
            int ko = kk * 4 + quad;
            bf16x8 af[4];
#pragma unroll
            for (int ni = 0; ni < 4; ++ni) {
                int row = ni * 16 + l16;
                af[ni] = Bv[row * 16 + (ko ^ (row & 7))];
            }
#pragma unroll
            for (int ni = 0; ni < 4; ++ni)
                acc[ch * 4 + ni] = __builtin_amdgcn_mfma_f32_16x16x32_bf16(
                    af[ni], sf[kk], acc[ch * 4 + ni], 0, 0, 0);
        }
        __syncthreads(); // prefetch complete + all reads of current Bs done
    }

    // epilogue: lane owns row m = bm0 + m_loc + l16 -> k = l16&3, b = m>>2.
    int m = bm0 + m_loc + l16;
    float* srow = scores + (size_t)(l16 & 3) * SC_K + (size_t)(m >> 2) * NVm1;
    float* mrow = maxs + (size_t)(m >> 2) * NVm1;
    if (full) {
#pragma unroll
        for (int ni = 0; ni < 32; ++ni) {
            int n0 = nbase + ni * 16 + quad * 4;
            f32x4 v = acc[ni];
            *(f32x4u*)&srow[n0] = v;
            f32x4 w;
#pragma unroll
            for (int c = 0; c < 4; ++c) {
                float t = fmaxf(v[c], __shfl_xor(v[c], 1));
                w[c] = fmaxf(t, __shfl_xor(t, 2));
            }
            if ((l16 & 3) == 0) *(f32x4u*)&mrow[n0] = w;
        }
    } else {
#pragma unroll
        for (int ni = 0; ni < 32; ++ni) {
            int n0 = nbase + ni * 16 + quad * 4;
            f32x4 v = acc[ni];
            f32x4 w;
#pragma unroll
            for (int c = 0; c < 4; ++c) {
                float t = fmaxf(v[c], __shfl_xor(v[c], 1));
                w[c] = fmaxf(t, __shfl_xor(t, 2));
            }
#pragma unroll
            for (int c = 0; c < 4; ++c) {
                if (n0 + c < NVm1) {
                    srow[n0 + c] = v[c];
                    if ((l16 & 3) == 0) mrow[n0 + c] = w[c];
                }
            }
        }
    }
}

extern "C" void kernel_launch(void* const* d_in, const int* in_sizes, int n_in,
                              void* d_out, int out_size, void* d_ws, size_t ws_size,
                              hipStream_t stream) {
    const float* hidden  = (const float*)d_in[0];
    const int*   mask    = (const int*)d_in[1];
    const float* pos_emb = (const float*)d_in[2];
    const float* w1      = (const float*)d_in[3];
    const float* w2      = (const float*)d_in[4];
    const float* glu1_w  = (const float*)d_in[5];
    const float* glu1_b  = (const float*)d_in[6];
    const float* att_w1  = (const float*)d_in[7];
    const float* att_w2  = (const float*)d_in[8];
    const float* att_v   = (const float*)d_in[9];
    const float* emb     = (const float*)d_in[10];

    float* out      = (float*)d_out;
    float* max_out  = out;                                   // [B, NVm1]
    float* loss_out = out + (size_t)NB * NVm1;               // scalar
    float* scores   = out + (size_t)NB * NVm1 + 1;           // [K, B, NVm1]

    char* w = (char*)d_ws;
    auto alloc = [&](size_t bytes) {
        char* p = w;
        w += (bytes + 255) & ~(size_t)255;
        return p;
    };
    // posPart/XbG padded to 64 rows / +64 rows so per-b megaf blocks (rows b*50..+63)
    // stay in-bounds; pad contents are garbage but clamped/masked in k_megaf.
    float* posPart = (float*)alloc((size_t)64 * ND * 4);
    float* hsW1    = (float*)alloc((size_t)NB * ND * 4);
    __hip_bfloat16* XbG     = (__hip_bfloat16*)alloc((size_t)(ROWS + 64) * ND * 2);
    __hip_bfloat16* w1h_t   = (__hip_bfloat16*)alloc((size_t)ND * ND * 2);
    __hip_bfloat16* attw2_t = (__hip_bfloat16*)alloc((size_t)ND * ND * 2);
    __hip_bfloat16* glu_t   = (__hip_bfloat16*)alloc((size_t)512 * ND * 2);
    __hip_bfloat16* selb    = (__hip_bfloat16*)alloc((size_t)MROWS * ND * 2);
    __hip_bfloat16* bnv     = (__hip_bfloat16*)alloc((size_t)NPAD2 * ND * 2);

    k_prep<<<G_TOT, 256, 0, stream>>>(hidden, mask, pos_emb, w1, att_w1, att_w2, glu1_w,
                                      emb, hsW1, posPart, XbG, w1h_t, attw2_t, glu_t,
                                      bnv, loss_out);
    k_megaf<<<NB, 256, 0, stream>>>(XbG, w1h_t, attw2_t, glu_t, hsW1, att_v, posPart,
                                    glu1_b, w2, mask, hidden, selb, loss_out);
    k_gemm<<<dim3(NPAD2 / GEMM_NSPAN, MROWS / 64), 256, 0, stream>>>(selb, bnv, scores, max_out);
}